// Round 4
// baseline (447.940 us; speedup 1.0000x reference)
//
#include <hip/hip_runtime.h>

#define BN 32768
#define IN 512
#define NE 8
#define NH 128
#define MO 256
#define RT 64     // rows per expert tile
#define KC1 32    // stage-1 k-chunk
#define XS_S 66   // xsT row stride (dwords): bank = 2k+lane -> 2-way, free
#define HS_S 66   // hsT row stride
#define GKC 32    // gate k-chunk
#define GS_S 261  // gate xsT stride: bank = 5k+row -> 2-way, free

// ---------------- gating: 256 rows/block, lane=row, W via s_load ------------
// f64 accumulation so top-2 ranking matches np at near-ties (proven r1-r3).
__global__ __launch_bounds__(256) void gate_kernel(
    const float* __restrict__ x, const float* __restrict__ wg,
    int* __restrict__ gcount, int* __restrict__ gload, float* __restrict__ gimp,
    int* __restrict__ idx_list, float* __restrict__ gate_list,
    float* __restrict__ out, const float* __restrict__ bout)
{
    __shared__ float gx[GKC][GS_S];      // 33.4 KB, transposed X chunk
    __shared__ int counts_s[NE];
    __shared__ int load_s[NE];
    __shared__ float imp_s[NE];
    __shared__ int base_s[NE];
    __shared__ int rec_e[512];
    __shared__ int rec_p[512];
    __shared__ float rec_g[512];

    int tid = threadIdx.x;
    if (tid < NE) { counts_s[tid] = 0; load_s[tid] = 0; imp_s[tid] = 0.f; }

    int row0g = blockIdx.x * 256;
    // staging assignment: 4 passes x 64 rows; 4 threads/row, 8 floats each
    int sr = tid >> 2;              // 0..63
    int sc = (tid & 3) * 8;         // 0,8,16,24

    // fused out-init (coalesced)
    {
        float2 bo = *(const float2*)bout;
        *(float2*)(out + (size_t)(row0g + tid) * 2) = bo;
    }

    double acc[NE];
    #pragma unroll
    for (int e = 0; e < NE; ++e) acc[e] = 0.0;

    // prefetch chunk 0
    float4 pf[4][2];
    #pragma unroll
    for (int p = 0; p < 4; ++p) {
        const float* r = x + (size_t)(row0g + p * 64 + sr) * IN + sc;
        pf[p][0] = *(const float4*)r;
        pf[p][1] = *(const float4*)(r + 4);
    }
    __syncthreads();   // counts_s init visible; gx not yet touched

    for (int c = 0; c < IN / GKC; ++c) {
        if (c) __syncthreads();
        #pragma unroll
        for (int p = 0; p < 4; ++p) {
            float v[8] = {pf[p][0].x, pf[p][0].y, pf[p][0].z, pf[p][0].w,
                          pf[p][1].x, pf[p][1].y, pf[p][1].z, pf[p][1].w};
            #pragma unroll
            for (int i = 0; i < 8; ++i) gx[sc + i][p * 64 + sr] = v[i];
        }
        __syncthreads();
        if (c + 1 < IN / GKC) {
            #pragma unroll
            for (int p = 0; p < 4; ++p) {
                const float* r = x + (size_t)(row0g + p * 64 + sr) * IN
                               + (c + 1) * GKC + sc;
                pf[p][0] = *(const float4*)r;
                pf[p][1] = *(const float4*)(r + 4);
            }
        }
        const float* wk0 = wg + c * GKC * NE;   // uniform -> s_load
        #pragma unroll 4
        for (int k = 0; k < GKC; ++k) {
            double xd = (double)gx[k][tid];     // lane=row read, 2-way free
            float4 wa = *(const float4*)(wk0 + k * NE);
            float4 wb = *(const float4*)(wk0 + k * NE + 4);
            acc[0] += xd * (double)wa.x; acc[1] += xd * (double)wa.y;
            acc[2] += xd * (double)wa.z; acc[3] += xd * (double)wa.w;
            acc[4] += xd * (double)wb.x; acc[5] += xd * (double)wb.y;
            acc[6] += xd * (double)wb.z; acc[7] += xd * (double)wb.w;
        }
    }

    // per-lane top-2 (lane owns its full row)
    int e0 = 0; double v0 = acc[0];
    #pragma unroll
    for (int e = 1; e < NE; ++e) if (acc[e] > v0) { v0 = acc[e]; e0 = e; }
    int e1 = (e0 == 0) ? 1 : 0; double v1 = acc[e1];
    #pragma unroll
    for (int e = 0; e < NE; ++e)
        if (e != e0 && acc[e] > v1) { v1 = acc[e]; e1 = e; }

    float t1 = expf((float)(v1 - v0));
    float s = 1.f + t1;
    float g0 = 1.f / s;
    float g1 = t1 / s;

    atomicAdd(&imp_s[e0], g0);
    atomicAdd(&imp_s[e1], g1);
    if (g0 > 0.f) atomicAdd(&load_s[e0], 1);
    if (g1 > 0.f) atomicAdd(&load_s[e1], 1);
    int p0 = atomicAdd(&counts_s[e0], 1);
    int p1 = atomicAdd(&counts_s[e1], 1);
    rec_e[tid * 2] = e0; rec_e[tid * 2 + 1] = e1;
    rec_g[tid * 2] = g0; rec_g[tid * 2 + 1] = g1;
    rec_p[tid * 2] = p0; rec_p[tid * 2 + 1] = p1;
    __syncthreads();

    if (tid < NE) {
        base_s[tid] = atomicAdd(&gcount[tid], counts_s[tid]);
        atomicAdd(&gimp[tid], imp_s[tid]);
        atomicAdd(&gload[tid], load_s[tid]);
    }
    __syncthreads();

    int row = row0g + tid;
    #pragma unroll
    for (int q = 0; q < 2; ++q) {
        int eq = rec_e[tid * 2 + q];
        int pos = base_s[eq] + rec_p[tid * 2 + q];
        idx_list[eq * BN + pos] = row;
        gate_list[eq * BN + pos] = rec_g[tid * 2 + q];
    }
}

// ---------------- loss ----------------
__global__ void loss_kernel(const float* __restrict__ gimp, const int* __restrict__ gload,
                            float* __restrict__ out) {
    if (threadIdx.x == 0 && blockIdx.x == 0) {
        float mi = 0.f, ml = 0.f;
        for (int e = 0; e < NE; ++e) { mi += gimp[e]; ml += (float)gload[e]; }
        mi *= 0.125f; ml *= 0.125f;
        float vi = 0.f, vl = 0.f;
        for (int e = 0; e < NE; ++e) {
            float d = gimp[e] - mi;  vi += d * d;
            float d2 = (float)gload[e] - ml; vl += d2 * d2;
        }
        vi *= (1.f / 7.f); vl *= (1.f / 7.f);
        float loss = (vi / (mi * mi + 1e-10f) + vl / (ml * ml + 1e-10f)) * 0.01f;
        out[BN * 2] = loss;
    }
}

// ---------------- expert: lane=row, weights via SGPR (s_load) ---------------
// Per k per wave: 1 ds_read_b32 (free 2-way) + N v_fmac(vacc, s_w, v_x).
// LDS pipe ~20% of FMA budget; scalar pipe carries all weight traffic.
__global__ __launch_bounds__(256) void expert_kernel(
    const float* __restrict__ x,
    const float* __restrict__ W1, const float* __restrict__ b1,
    const float* __restrict__ W2, const float* __restrict__ b2,
    const float* __restrict__ Wout,
    const int* __restrict__ gcount,
    const int* __restrict__ idx_list, const float* __restrict__ gate_list,
    float* __restrict__ out)
{
    __shared__ float xsT[KC1][XS_S];    // 8.25 KB
    __shared__ float hsT[NH][HS_S];     // 33 KB
    __shared__ float mred[4][64];
    __shared__ float sred[4][64];
    __shared__ float w0red[4][64];
    __shared__ float w1red[4][64];

    int e = blockIdx.y;
    int cnt = gcount[e];
    int row0 = blockIdx.x * RT;
    if (row0 >= cnt) return;          // uniform exit, before any barrier
    int tid = threadIdx.x;
    int lane = tid & 63;
    int w = __builtin_amdgcn_readfirstlane(tid >> 6);  // uniform wave id

    // staging: 4 threads/row, 8 floats each
    int sr = tid >> 2;
    int sc = (tid & 3) * 8;
    int sgi = row0 + sr; if (sgi >= cnt) sgi = cnt - 1;
    const float* xrow = x + (size_t)idx_list[e * BN + sgi] * IN;

    const float* W1e = W1 + (size_t)e * IN * NH;
    const float* W2e = W2 + (size_t)e * NH * MO;

    // ---- stage 1: wave w -> cols [32w, 32w+32), acc over all k ----
    float acc1[32] = {};
    float4 px0 = *(const float4*)(xrow + sc);
    float4 px1 = *(const float4*)(xrow + sc + 4);

    for (int c = 0; c < IN / KC1; ++c) {
        if (c) __syncthreads();
        {
            float v[8] = {px0.x, px0.y, px0.z, px0.w, px1.x, px1.y, px1.z, px1.w};
            #pragma unroll
            for (int i = 0; i < 8; ++i) xsT[sc + i][sr] = v[i];
        }
        __syncthreads();
        if (c + 1 < IN / KC1) {
            const float* nx = xrow + (c + 1) * KC1 + sc;
            px0 = *(const float4*)nx;
            px1 = *(const float4*)(nx + 4);
        }
        const float* Wc = W1e + (size_t)c * KC1 * NH + w * 32;  // uniform
        #pragma unroll 2
        for (int k = 0; k < KC1; ++k) {
            float xv = xsT[k][lane];
            const float4* wk = (const float4*)(Wc + (size_t)k * NH);
            #pragma unroll
            for (int j4 = 0; j4 < 8; ++j4) {
                float4 wv = wk[j4];
                acc1[j4 * 4 + 0] = fmaf(xv, wv.x, acc1[j4 * 4 + 0]);
                acc1[j4 * 4 + 1] = fmaf(xv, wv.y, acc1[j4 * 4 + 1]);
                acc1[j4 * 4 + 2] = fmaf(xv, wv.z, acc1[j4 * 4 + 2]);
                acc1[j4 * 4 + 3] = fmaf(xv, wv.w, acc1[j4 * 4 + 3]);
            }
        }
    }

    // relu + b1 -> hsT[col][row]; bank = 2j+lane -> 2-way, free
    {
        const float* b1e = b1 + e * NH + w * 32;   // uniform
        #pragma unroll
        for (int j = 0; j < 32; ++j)
            hsT[w * 32 + j][lane] = fmaxf(acc1[j] + b1e[j], 0.f);
    }
    __syncthreads();

    // ---- stage 2: wave w -> cols [64w, 64w+64), k = 0..127 from hsT ----
    float acc2[64] = {};
    const float* W2c = W2e + w * 64;               // uniform
    #pragma unroll 2
    for (int k = 0; k < NH; ++k) {
        float hv = hsT[k][lane];
        const float4* wk = (const float4*)(W2c + (size_t)k * MO);
        #pragma unroll
        for (int j4 = 0; j4 < 16; ++j4) {
            float4 wv = wk[j4];
            acc2[j4 * 4 + 0] = fmaf(hv, wv.x, acc2[j4 * 4 + 0]);
            acc2[j4 * 4 + 1] = fmaf(hv, wv.y, acc2[j4 * 4 + 1]);
            acc2[j4 * 4 + 2] = fmaf(hv, wv.z, acc2[j4 * 4 + 2]);
            acc2[j4 * 4 + 3] = fmaf(hv, wv.w, acc2[j4 * 4 + 3]);
        }
    }

    // ---- epilogue: softmax over 256 (4 waves x 64 cols), fused @Wout ----
    {
        const float* b2e = b2 + e * MO + w * 64;   // uniform
        float m = -1e30f;
        #pragma unroll
        for (int j = 0; j < 64; ++j) {
            acc2[j] += b2e[j];
            m = fmaxf(m, acc2[j]);
        }
        mred[w][lane] = m;
    }
    __syncthreads();
    float M = fmaxf(fmaxf(mred[0][lane], mred[1][lane]),
                    fmaxf(mred[2][lane], mred[3][lane]));
    {
        const float* wo = Wout + (size_t)w * 64 * 2;  // uniform
        float s = 0.f, a0 = 0.f, a1 = 0.f;
        #pragma unroll
        for (int j = 0; j < 64; ++j) {
            float t = __expf(acc2[j] - M);
            s += t;
            a0 = fmaf(t, wo[j * 2 + 0], a0);
            a1 = fmaf(t, wo[j * 2 + 1], a1);
        }
        sred[w][lane] = s;
        w0red[w][lane] = a0;
        w1red[w][lane] = a1;
    }
    __syncthreads();
    if (w == 0) {
        int gi = row0 + lane;
        if (gi < cnt) {
            float S  = sred[0][lane] + sred[1][lane] + sred[2][lane] + sred[3][lane];
            float A0 = w0red[0][lane] + w0red[1][lane] + w0red[2][lane] + w0red[3][lane];
            float A1 = w1red[0][lane] + w1red[1][lane] + w1red[2][lane] + w1red[3][lane];
            float g = gate_list[e * BN + gi];
            int brow = idx_list[e * BN + gi];
            float inv = 1.f / S;
            atomicAdd(&out[brow * 2 + 0], g * A0 * inv);
            atomicAdd(&out[brow * 2 + 1], g * A1 * inv);
        }
    }
}

extern "C" void kernel_launch(void* const* d_in, const int* in_sizes, int n_in,
                              void* d_out, int out_size, void* d_ws, size_t ws_size,
                              hipStream_t stream) {
    const float* x    = (const float*)d_in[0];
    // d_in[1] = cat_prop, unused by the reference
    const float* wg   = (const float*)d_in[2];
    const float* W1   = (const float*)d_in[3];
    const float* b1   = (const float*)d_in[4];
    const float* W2   = (const float*)d_in[5];
    const float* b2   = (const float*)d_in[6];
    const float* Wout = (const float*)d_in[7];
    const float* bout = (const float*)d_in[8];
    float* out = (float*)d_out;

    char* ws = (char*)d_ws;
    int*   gcount    = (int*)(ws + 0);
    int*   gload     = (int*)(ws + 32);
    float* gimp      = (float*)(ws + 64);
    int*   idx_list  = (int*)(ws + 128);
    float* gate_list = (float*)(ws + 128 + sizeof(int) * NE * BN);

    hipMemsetAsync(ws, 0, 128, stream);
    gate_kernel<<<BN / 256, 256, 0, stream>>>(x, wg, gcount, gload, gimp,
                                              idx_list, gate_list, out, bout);
    loss_kernel<<<1, 64, 0, stream>>>(gimp, gload, out);
    dim3 eg(BN / RT, NE);
    expert_kernel<<<eg, 256, 0, stream>>>(x, W1, b1, W2, b2, Wout,
                                          gcount, idx_list, gate_list, out);
}

// Round 5
// 415.348 us; speedup vs baseline: 1.0785x; 1.0785x over previous
//
#include <hip/hip_runtime.h>

#define BN 32768
#define IN 512
#define NE 8
#define NH 128
#define MO 256
#define RT 128    // rows per expert tile
#define KC1 32    // stage-1 k-chunk
#define KC2 16    // stage-2 k-chunk
#define XS_S 129  // xsT row stride (odd -> transposed scalar writes 2-way free)
#define WS_S 144  // ws1 row stride (col-group padded layout, see fofs)
#define HS_S 129
#define W2_S 144
#define GR 64     // gate rows per block
#define GCH 256   // gate k-chunk
#define GX_S 261  // gate x stride (5 mod 32 -> reads/writes 2-way free)

// col-group offset: 8g + 4*(g>>2). Spreads the 16 col-groups over banks
// {0,4,..,28} each hit exactly 2x -> 2-way (free) B-reads instead of 4-way.
__device__ __forceinline__ int fofs(int g) { return g * 8 + ((g >> 2) << 2); }

// ---------------- gating: 64 rows/block, k sliced across 4 waves -----------
// f64 accumulation so top-2 ranking matches np at near-ties (proven r1-r4).
__global__ __launch_bounds__(256) void gate_kernel(
    const float* __restrict__ x, const float* __restrict__ wg,
    int* __restrict__ gcount, int* __restrict__ gload, float* __restrict__ gimp,
    int* __restrict__ idx_list, float* __restrict__ gate_list,
    float* __restrict__ out, const float* __restrict__ bout)
{
    __shared__ __align__(16) unsigned char gsm[GR * GX_S * 4];  // 66816 B
    float (*gx)[GX_S] = (float (*)[GX_S])gsm;
    double* prd = (double*)gsm;                    // [8][256], aliases gx
    int*   counts_s = (int*)(gsm + 20480);
    int*   load_s   = (int*)(gsm + 20512);
    float* imp_s    = (float*)(gsm + 20544);
    int*   base_s   = (int*)(gsm + 20576);

    int tid = threadIdx.x;
    int row0 = blockIdx.x * GR;

    if (tid < 2 * GR) {  // fused out-init, coalesced
        out[(size_t)(row0 + (tid >> 1)) * 2 + (tid & 1)] = bout[tid & 1];
    }

    int lane = tid & 63;
    int w = __builtin_amdgcn_readfirstlane(tid >> 6);  // k-slice / wave id
    int sr = tid >> 2, sf = tid & 3;                   // staging: 4 th/row
    const float* xsrc = x + (size_t)(row0 + sr) * IN;

    double acc[NE];
    #pragma unroll
    for (int e = 0; e < NE; ++e) acc[e] = 0.0;

    for (int c = 0; c < IN / GCH; ++c) {
        if (c) __syncthreads();
        #pragma unroll
        for (int p = 0; p < 16; ++p) {
            float4 v = *(const float4*)(xsrc + c * GCH + sf * 64 + p * 4);
            *(float4*)&gx[sr][sf * 65 + p * 4] = v;   // 65-float sub-blocks
        }
        __syncthreads();
        const float* wp = wg + (size_t)(c * GCH + w * 64) * NE;  // uniform
        #pragma unroll 2
        for (int k4 = 0; k4 < 16; ++k4) {
            float4 xv = *(const float4*)&gx[lane][w * 65 + k4 * 4];
            float xa[4] = {xv.x, xv.y, xv.z, xv.w};
            #pragma unroll
            for (int j = 0; j < 4; ++j) {
                double xd = (double)xa[j];
                const float* wk = wp + (k4 * 4 + j) * NE;
                #pragma unroll
                for (int e = 0; e < NE; ++e)
                    acc[e] += xd * (double)wk[e];
            }
        }
    }
    __syncthreads();                 // all gx reads done; gx region now dead
    #pragma unroll
    for (int e = 0; e < NE; ++e) prd[e * 256 + tid] = acc[e];
    if (tid < NE) { counts_s[tid] = 0; load_s[tid] = 0; imp_s[tid] = 0.f; }
    __syncthreads();

    int e0 = 0, e1 = 1, p0 = 0, p1 = 0;
    float g0 = 0.f, g1 = 0.f;
    if (tid < GR) {
        double a2[NE];
        #pragma unroll
        for (int e = 0; e < NE; ++e)
            a2[e] = prd[e * 256 + tid] + prd[e * 256 + tid + 64]
                  + prd[e * 256 + tid + 128] + prd[e * 256 + tid + 192];
        double v0 = a2[0]; e0 = 0;
        #pragma unroll
        for (int e = 1; e < NE; ++e) if (a2[e] > v0) { v0 = a2[e]; e0 = e; }
        e1 = (e0 == 0) ? 1 : 0; double v1 = a2[e1];
        #pragma unroll
        for (int e = 0; e < NE; ++e)
            if (e != e0 && a2[e] > v1) { v1 = a2[e]; e1 = e; }
        float t1 = expf((float)(v1 - v0));
        float s = 1.f + t1;
        g0 = 1.f / s;
        g1 = t1 / s;
        atomicAdd(&imp_s[e0], g0);
        atomicAdd(&imp_s[e1], g1);
        if (g0 > 0.f) atomicAdd(&load_s[e0], 1);
        if (g1 > 0.f) atomicAdd(&load_s[e1], 1);
        p0 = atomicAdd(&counts_s[e0], 1);
        p1 = atomicAdd(&counts_s[e1], 1);
    }
    __syncthreads();
    if (tid < NE) {
        base_s[tid] = atomicAdd(&gcount[tid], counts_s[tid]);
        atomicAdd(&gimp[tid], imp_s[tid]);
        atomicAdd(&gload[tid], load_s[tid]);
    }
    __syncthreads();
    if (tid < GR) {
        int row = row0 + tid;
        idx_list[e0 * BN + base_s[e0] + p0] = row;
        gate_list[e0 * BN + base_s[e0] + p0] = g0;
        idx_list[e1 * BN + base_s[e1] + p1] = row;
        gate_list[e1 * BN + base_s[e1] + p1] = g1;
    }
}

// ---------------- loss ----------------
__global__ void loss_kernel(const float* __restrict__ gimp, const int* __restrict__ gload,
                            float* __restrict__ out) {
    if (threadIdx.x == 0 && blockIdx.x == 0) {
        float mi = 0.f, ml = 0.f;
        for (int e = 0; e < NE; ++e) { mi += gimp[e]; ml += (float)gload[e]; }
        mi *= 0.125f; ml *= 0.125f;
        float vi = 0.f, vl = 0.f;
        for (int e = 0; e < NE; ++e) {
            float d = gimp[e] - mi;  vi += d * d;
            float d2 = (float)gload[e] - ml; vl += d2 * d2;
        }
        vi *= (1.f / 7.f); vl *= (1.f / 7.f);
        float loss = (vi / (mi * mi + 1e-10f) + vl / (ml * ml + 1e-10f)) * 0.01f;
        out[BN * 2] = loss;
    }
}

// ---------------- expert: 128-row tile, 8x8 micro-tile, register prefetch ---
// LDS-pipe-balanced: 8x8 needs 4 b128 per 64 lane-FMA (per-CU LDS ~1.1-1.5x
// FMA wall vs r2's 2.3x). Register prefetch avoids the vmcnt(0) barrier drain.
__global__ __launch_bounds__(256) void expert_kernel(
    const float* __restrict__ x,
    const float* __restrict__ W1, const float* __restrict__ b1,
    const float* __restrict__ W2, const float* __restrict__ b2,
    const float* __restrict__ Wout,
    const int* __restrict__ gcount,
    const int* __restrict__ idx_list, const float* __restrict__ gate_list,
    float* __restrict__ out)
{
    __shared__ __align__(16) union {
        struct { float xsT[KC1][XS_S]; float ws1[KC1][WS_S]; } s1; // 34944 B
        struct { float hsT[NH][HS_S];  float w2s[KC2][W2_S]; } s2; // 75264 B
    } sm;
    __shared__ __align__(16) float pr[RT][8];                      // 4096 B

    int e = blockIdx.y;
    int cnt = gcount[e];
    int row0 = blockIdx.x * RT;
    if (row0 >= cnt) return;            // uniform exit before any barrier
    int tid = threadIdx.x;
    int tx = tid & 15;                  // col group (8 cols)
    int ty = tid >> 4;                  // row group (8 rows)

    // X staging: 2 threads/row, 16 floats each per chunk
    int sr = tid >> 1, sh = tid & 1;
    int sgi = row0 + sr; if (sgi >= cnt) sgi = cnt - 1;
    const float* xrow = x + (size_t)idx_list[e * BN + sgi] * IN;
    // W1 staging: 16 col-groups x 2 k-rows per thread
    int wg1 = tid & 15, wk1 = (tid >> 4) * 2;
    // W2 staging: 16 col-groups x 1 k-row
    int wg2 = tid & 15, wk2 = tid >> 4;

    const float* W1e = W1 + (size_t)e * IN * NH;
    const float* W2e = W2 + (size_t)e * NH * MO;

    // ---- stage 1: H[128x128] = relu(X @ W1 + b1) ----
    float c1[8][8] = {};
    float4 px[4], pw[4];
    #pragma unroll
    for (int p = 0; p < 4; ++p) px[p] = *(const float4*)(xrow + sh * 16 + p * 4);
    #pragma unroll
    for (int q = 0; q < 2; ++q) {
        const float* wsrc = W1e + (size_t)(wk1 + q) * NH + wg1 * 8;
        pw[q * 2]     = *(const float4*)wsrc;
        pw[q * 2 + 1] = *(const float4*)(wsrc + 4);
    }

    for (int c = 0; c < IN / KC1; ++c) {
        if (c) __syncthreads();
        #pragma unroll
        for (int p = 0; p < 4; ++p) {      // transposed scalar stores, 2-way
            float v[4] = {px[p].x, px[p].y, px[p].z, px[p].w};
            #pragma unroll
            for (int j = 0; j < 4; ++j)
                sm.s1.xsT[sh * 16 + p * 4 + j][sr] = v[j];
        }
        #pragma unroll
        for (int q = 0; q < 2; ++q) {
            *(float4*)&sm.s1.ws1[wk1 + q][fofs(wg1)]     = pw[q * 2];
            *(float4*)&sm.s1.ws1[wk1 + q][fofs(wg1) + 4] = pw[q * 2 + 1];
        }
        __syncthreads();
        if (c + 1 < IN / KC1) {            // prefetch next chunk (reg, no drain)
            int k0n = (c + 1) * KC1;
            #pragma unroll
            for (int p = 0; p < 4; ++p)
                px[p] = *(const float4*)(xrow + k0n + sh * 16 + p * 4);
            #pragma unroll
            for (int q = 0; q < 2; ++q) {
                const float* wsrc = W1e + (size_t)(k0n + wk1 + q) * NH + wg1 * 8;
                pw[q * 2]     = *(const float4*)wsrc;
                pw[q * 2 + 1] = *(const float4*)(wsrc + 4);
            }
        }
        #pragma unroll 4
        for (int k = 0; k < KC1; ++k) {
            float4 a0  = *(const float4*)&sm.s1.xsT[k][ty * 8];
            float4 a1  = *(const float4*)&sm.s1.xsT[k][ty * 8 + 4];
            float4 b0  = *(const float4*)&sm.s1.ws1[k][fofs(tx)];
            float4 b1v = *(const float4*)&sm.s1.ws1[k][fofs(tx) + 4];
            float a[8] = {a0.x, a0.y, a0.z, a0.w, a1.x, a1.y, a1.z, a1.w};
            float b[8] = {b0.x, b0.y, b0.z, b0.w, b1v.x, b1v.y, b1v.z, b1v.w};
            #pragma unroll
            for (int i = 0; i < 8; ++i)
                #pragma unroll
                for (int j = 0; j < 8; ++j)
                    c1[i][j] = fmaf(a[i], b[j], c1[i][j]);
        }
    }
    __syncthreads();                       // stage-1 LDS reads done

    {   // relu + b1 -> hsT[col][row]
        float4 bl = *(const float4*)(b1 + e * NH + tx * 8);
        float4 bh = *(const float4*)(b1 + e * NH + tx * 8 + 4);
        float bb[8] = {bl.x, bl.y, bl.z, bl.w, bh.x, bh.y, bh.z, bh.w};
        #pragma unroll
        for (int i = 0; i < 8; ++i)
            #pragma unroll
            for (int j = 0; j < 8; ++j)
                sm.s2.hsT[tx * 8 + j][ty * 8 + i] = fmaxf(c1[i][j] + bb[j], 0.f);
    }

    // ---- stage 2: two col-passes of Z[128x128], online-softmax merge ----
    for (int P = 0; P < 2; ++P) {
        float z[8][8] = {};
        float4 pw2[2];
        {
            const float* wsrc = W2e + (size_t)wk2 * MO + P * 128 + wg2 * 8;
            pw2[0] = *(const float4*)wsrc;
            pw2[1] = *(const float4*)(wsrc + 4);
        }
        for (int c = 0; c < NH / KC2; ++c) {
            __syncthreads();               // prev chunk consumed / hsT published
            *(float4*)&sm.s2.w2s[wk2][fofs(wg2)]     = pw2[0];
            *(float4*)&sm.s2.w2s[wk2][fofs(wg2) + 4] = pw2[1];
            __syncthreads();
            if (c + 1 < NH / KC2) {
                const float* wsrc = W2e + (size_t)((c + 1) * KC2 + wk2) * MO
                                  + P * 128 + wg2 * 8;
                pw2[0] = *(const float4*)wsrc;
                pw2[1] = *(const float4*)(wsrc + 4);
            }
            #pragma unroll 4
            for (int k = 0; k < KC2; ++k) {
                float4 a0  = *(const float4*)&sm.s2.hsT[c * KC2 + k][ty * 8];
                float4 a1  = *(const float4*)&sm.s2.hsT[c * KC2 + k][ty * 8 + 4];
                float4 b0  = *(const float4*)&sm.s2.w2s[k][fofs(tx)];
                float4 b1v = *(const float4*)&sm.s2.w2s[k][fofs(tx) + 4];
                float a[8] = {a0.x, a0.y, a0.z, a0.w, a1.x, a1.y, a1.z, a1.w};
                float b[8] = {b0.x, b0.y, b0.z, b0.w, b1v.x, b1v.y, b1v.z, b1v.w};
                #pragma unroll
                for (int i = 0; i < 8; ++i)
                    #pragma unroll
                    for (int j = 0; j < 8; ++j)
                        z[i][j] = fmaf(a[i], b[j], z[i][j]);
            }
        }
        // per-pass softmax partials (local max), reduced across tx via shfl16
        float4 bl = *(const float4*)(b2 + e * MO + P * 128 + tx * 8);
        float4 bh = *(const float4*)(b2 + e * MO + P * 128 + tx * 8 + 4);
        float bz[8] = {bl.x, bl.y, bl.z, bl.w, bh.x, bh.y, bh.z, bh.w};
        const float* wop = Wout + (size_t)(P * 128 + tx * 8) * 2;
        float4 q0 = *(const float4*)wop,       q1 = *(const float4*)(wop + 4);
        float4 q2 = *(const float4*)(wop + 8), q3 = *(const float4*)(wop + 12);
        float wo0[8] = {q0.x, q0.z, q1.x, q1.z, q2.x, q2.z, q3.x, q3.z};
        float wo1[8] = {q0.y, q0.w, q1.y, q1.w, q2.y, q2.w, q3.y, q3.w};
        #pragma unroll
        for (int i = 0; i < 8; ++i) {
            float m = -1e30f;
            #pragma unroll
            for (int j = 0; j < 8; ++j) { z[i][j] += bz[j]; m = fmaxf(m, z[i][j]); }
            #pragma unroll
            for (int mk = 1; mk < 16; mk <<= 1) m = fmaxf(m, __shfl_xor(m, mk, 16));
            float s = 0.f, w0 = 0.f, w1 = 0.f;
            #pragma unroll
            for (int j = 0; j < 8; ++j) {
                float t = __expf(z[i][j] - m);
                s += t;
                w0 = fmaf(t, wo0[j], w0);
                w1 = fmaf(t, wo1[j], w1);
            }
            #pragma unroll
            for (int mk = 1; mk < 16; mk <<= 1) {
                s  += __shfl_xor(s,  mk, 16);
                w0 += __shfl_xor(w0, mk, 16);
                w1 += __shfl_xor(w1, mk, 16);
            }
            if (tx == 0)
                *(float4*)&pr[ty * 8 + i][P * 4] = make_float4(m, s, w0, w1);
        }
    }
    __syncthreads();

    // ---- final: exact merge of the two passes, fused gate + atomics ----
    if (tid < RT) {
        float4 p0v = *(const float4*)&pr[tid][0];
        float4 p1v = *(const float4*)&pr[tid][4];
        float M  = fmaxf(p0v.x, p1v.x);
        float f0 = __expf(p0v.x - M), f1 = __expf(p1v.x - M);
        float S  = p0v.y * f0 + p1v.y * f1;
        float A0 = p0v.z * f0 + p1v.z * f1;
        float A1 = p0v.w * f0 + p1v.w * f1;
        int gi = row0 + tid;
        if (gi < cnt) {
            float g = gate_list[e * BN + gi];
            int brow = idx_list[e * BN + gi];
            float inv = 1.f / S;
            atomicAdd(&out[brow * 2 + 0], g * A0 * inv);
            atomicAdd(&out[brow * 2 + 1], g * A1 * inv);
        }
    }
}

extern "C" void kernel_launch(void* const* d_in, const int* in_sizes, int n_in,
                              void* d_out, int out_size, void* d_ws, size_t ws_size,
                              hipStream_t stream) {
    const float* x    = (const float*)d_in[0];
    // d_in[1] = cat_prop, unused by the reference
    const float* wg   = (const float*)d_in[2];
    const float* W1   = (const float*)d_in[3];
    const float* b1   = (const float*)d_in[4];
    const float* W2   = (const float*)d_in[5];
    const float* b2   = (const float*)d_in[6];
    const float* Wout = (const float*)d_in[7];
    const float* bout = (const float*)d_in[8];
    float* out = (float*)d_out;

    char* ws = (char*)d_ws;
    int*   gcount    = (int*)(ws + 0);
    int*   gload     = (int*)(ws + 32);
    float* gimp      = (float*)(ws + 64);
    int*   idx_list  = (int*)(ws + 128);
    float* gate_list = (float*)(ws + 128 + sizeof(int) * NE * BN);

    hipMemsetAsync(ws, 0, 128, stream);
    gate_kernel<<<BN / GR, 256, 0, stream>>>(x, wg, gcount, gload, gimp,
                                             idx_list, gate_list, out, bout);
    loss_kernel<<<1, 64, 0, stream>>>(gimp, gload, out);
    dim3 eg(BN / RT, NE);
    expert_kernel<<<eg, 256, 0, stream>>>(x, W1, b1, W2, b2, Wout,
                                          gcount, idx_list, gate_list, out);
}

// Round 6
// 347.822 us; speedup vs baseline: 1.2878x; 1.1941x over previous
//
#include <hip/hip_runtime.h>

#define BN 32768
#define IN 512
#define NE 8
#define NH 128
#define MO 256
#define RT 64     // rows per expert tile
#define KC1 64    // stage-1 k-chunk
#define KC2 16    // stage-2 k-chunk
#define XS_S 68   // xs row stride: A-reads 2-way (free); 68%4==0 keeps b128 align

typedef const __attribute__((address_space(1))) unsigned int gu32;
typedef __attribute__((address_space(3))) unsigned int lu32;
__device__ __forceinline__ void cp16(const float* g, float* l) {
    __builtin_amdgcn_global_load_lds((gu32*)g, (lu32*)l, 16, 0, 0);
}

// ---------------- gating: 128 rows/block, k-split 2, wg in LDS --------------
// f64 accumulation so top-2 ranking matches np at near-ties (proven r1-r5).
__global__ __launch_bounds__(256) void gate_kernel(
    const float* __restrict__ x, const float* __restrict__ wg,
    int* __restrict__ gcount, int* __restrict__ gload, float* __restrict__ gimp,
    int* __restrict__ idx_list, float* __restrict__ gate_list,
    float* __restrict__ out, const float* __restrict__ bout)
{
    __shared__ float wgs[IN * NE];          // 16 KB
    __shared__ double prt[2][128][NE];      // 16 KB
    __shared__ int counts_s[NE];
    __shared__ int load_s[NE];
    __shared__ float imp_s[NE];
    __shared__ int base_s[NE];

    int tid = threadIdx.x;
    int row0 = blockIdx.x * 128;

    // stage wg (16 KB, coalesced float4)
    #pragma unroll
    for (int p = 0; p < 4; ++p)
        ((float4*)wgs)[p * 256 + tid] = ((const float4*)wg)[p * 256 + tid];
    if (tid < NE) { counts_s[tid] = 0; load_s[tid] = 0; imp_s[tid] = 0.f; }
    // fused out-init: 128 rows x 2
    out[(size_t)row0 * 2 + tid] = bout[tid & 1];
    __syncthreads();

    int r = tid & 127, h = tid >> 7;        // h wave-uniform (waves 0,1 vs 2,3)
    const float* xr = x + (size_t)(row0 + r) * IN + h * 256;
    int hk = h * 256;

    double acc[NE];
    #pragma unroll
    for (int e = 0; e < NE; ++e) acc[e] = 0.0;

    for (int k0 = 0; k0 < 256; k0 += 16) {  // one 64B line per thread per iter
        float4 xv[4];
        #pragma unroll
        for (int p = 0; p < 4; ++p) xv[p] = *(const float4*)(xr + k0 + p * 4);
        #pragma unroll
        for (int p = 0; p < 4; ++p) {
            float xa[4] = {xv[p].x, xv[p].y, xv[p].z, xv[p].w};
            #pragma unroll
            for (int j = 0; j < 4; ++j) {
                double xd = (double)xa[j];
                const float* wk = wgs + (hk + k0 + p * 4 + j) * NE; // broadcast
                #pragma unroll
                for (int e = 0; e < NE; ++e)
                    acc[e] += xd * (double)wk[e];
            }
        }
    }
    #pragma unroll
    for (int e = 0; e < NE; ++e) prt[h][r][e] = acc[e];
    __syncthreads();

    int e0 = 0, e1 = 1, p0 = 0, p1 = 0;
    float g0 = 0.f, g1 = 0.f;
    if (tid < 128) {
        double a2[NE];
        #pragma unroll
        for (int e = 0; e < NE; ++e) a2[e] = prt[0][tid][e] + prt[1][tid][e];
        double v0 = a2[0]; e0 = 0;
        #pragma unroll
        for (int e = 1; e < NE; ++e) if (a2[e] > v0) { v0 = a2[e]; e0 = e; }
        e1 = (e0 == 0) ? 1 : 0; double v1 = a2[e1];
        #pragma unroll
        for (int e = 0; e < NE; ++e)
            if (e != e0 && a2[e] > v1) { v1 = a2[e]; e1 = e; }
        float t1 = expf((float)(v1 - v0));
        float s = 1.f + t1;
        g0 = 1.f / s;
        g1 = t1 / s;
        atomicAdd(&imp_s[e0], g0);
        atomicAdd(&imp_s[e1], g1);
        if (g0 > 0.f) atomicAdd(&load_s[e0], 1);
        if (g1 > 0.f) atomicAdd(&load_s[e1], 1);
        p0 = atomicAdd(&counts_s[e0], 1);
        p1 = atomicAdd(&counts_s[e1], 1);
    }
    __syncthreads();
    if (tid < NE) {
        base_s[tid] = atomicAdd(&gcount[tid], counts_s[tid]);
        atomicAdd(&gimp[tid], imp_s[tid]);
        atomicAdd(&gload[tid], load_s[tid]);
    }
    __syncthreads();
    if (tid < 128) {
        int row = row0 + tid;
        idx_list[e0 * BN + base_s[e0] + p0] = row;
        gate_list[e0 * BN + base_s[e0] + p0] = g0;
        idx_list[e1 * BN + base_s[e1] + p1] = row;
        gate_list[e1 * BN + base_s[e1] + p1] = g1;
    }
}

// ---------------- loss ----------------
__global__ void loss_kernel(const float* __restrict__ gimp, const int* __restrict__ gload,
                            float* __restrict__ out) {
    if (threadIdx.x == 0 && blockIdx.x == 0) {
        float mi = 0.f, ml = 0.f;
        for (int e = 0; e < NE; ++e) { mi += gimp[e]; ml += (float)gload[e]; }
        mi *= 0.125f; ml *= 0.125f;
        float vi = 0.f, vl = 0.f;
        for (int e = 0; e < NE; ++e) {
            float d = gimp[e] - mi;  vi += d * d;
            float d2 = (float)gload[e] - ml; vl += d2 * d2;
        }
        vi *= (1.f / 7.f); vl *= (1.f / 7.f);
        float loss = (vi / (mi * mi + 1e-10f) + vl / (ml * ml + 1e-10f)) * 0.01f;
        out[BN * 2] = loss;
    }
}

// ---------------- expert: 64-row tile; 4x8 / 8x8 micro-tiles ----------------
// Every B access is the r2-proven CONTIGUOUS wave pattern (0 conflicts).
// The 8 cols per thread = two contiguous 4-col groups. W2/X register-
// prefetched after the publish barrier (in flight during compute); W1 via
// cp16 (zero reg cost). LDS 50176 B -> 3 blocks/CU.
__global__ __launch_bounds__(256, 2) void expert_kernel(
    const float* __restrict__ x,
    const float* __restrict__ W1, const float* __restrict__ b1,
    const float* __restrict__ W2, const float* __restrict__ b2,
    const float* __restrict__ Wout,
    const int* __restrict__ gcount,
    const int* __restrict__ idx_list, const float* __restrict__ gate_list,
    float* __restrict__ out)
{
    __shared__ __align__(16) union {
        struct { float xs[RT][XS_S]; float ws1[KC1][NH]; } s1; // 17408+32768
        struct { float hs[RT][NH];   float w2s[KC2][MO]; } s2; // 32768+16384
    } sm;

    int e = blockIdx.y;
    int cnt = gcount[e];
    int row0 = blockIdx.x * RT;
    if (row0 >= cnt) return;            // uniform exit before any barrier
    int tid = threadIdx.x;
    int tx1 = tid & 15, ty1 = tid >> 4; // stage1: 4 rows x {tx1*4, 64+tx1*4}
    int tx2 = tid & 31, ty2 = tid >> 5; // stage2: 8 rows x {tx2*4, 128+tx2*4}

    int sr = tid >> 2, sf = tid & 3;    // X staging: 4 threads/row
    int sgi = row0 + sr; if (sgi >= cnt) sgi = cnt - 1;
    const float* xrow = x + (size_t)idx_list[e * BN + sgi] * IN;

    const float* W1e = W1 + (size_t)e * IN * NH;
    const float* W2e = W2 + (size_t)e * NH * MO;

    // ---- stage 1: H[64x128] = relu(X @ W1 + b1) ----
    float c1[4][8] = {};
    float4 px[4];
    #pragma unroll
    for (int p = 0; p < 4; ++p)
        px[p] = *(const float4*)(xrow + p * 16 + sf * 4);

    for (int c = 0; c < IN / KC1; ++c) {
        if (c) __syncthreads();                 // prev chunk fully consumed
        #pragma unroll
        for (int p = 0; p < 4; ++p)
            *(float4*)&sm.s1.xs[sr][p * 16 + sf * 4] = px[p];
        {   // W1 chunk: contiguous 32 KB via async DMA
            const float* g = W1e + (size_t)c * KC1 * NH;
            float* l = &sm.s1.ws1[0][0];
            #pragma unroll
            for (int p = 0; p < 8; ++p)
                cp16(g + p * 1024 + tid * 4, l + p * 1024 + tid * 4);
        }
        __syncthreads();                        // publish chunk c
        if (c + 1 < IN / KC1) {                 // X prefetch flies over compute
            const float* nx = xrow + (c + 1) * KC1;
            #pragma unroll
            for (int p = 0; p < 4; ++p)
                px[p] = *(const float4*)(nx + p * 16 + sf * 4);
        }
        #pragma unroll 2
        for (int kq = 0; kq < KC1 / 4; ++kq) {
            float a[4][4];
            #pragma unroll
            for (int i = 0; i < 4; ++i) {
                float4 av = *(const float4*)&sm.s1.xs[ty1 * 4 + i][kq * 4];
                a[i][0] = av.x; a[i][1] = av.y; a[i][2] = av.z; a[i][3] = av.w;
            }
            #pragma unroll
            for (int kk = 0; kk < 4; ++kk) {
                float4 blo = *(const float4*)&sm.s1.ws1[kq * 4 + kk][tx1 * 4];
                float4 bhi = *(const float4*)&sm.s1.ws1[kq * 4 + kk][64 + tx1 * 4];
                float bl[4] = {blo.x, blo.y, blo.z, blo.w};
                float bh[4] = {bhi.x, bhi.y, bhi.z, bhi.w};
                #pragma unroll
                for (int i = 0; i < 4; ++i)
                    #pragma unroll
                    for (int j = 0; j < 4; ++j) {
                        c1[i][j]     = fmaf(a[i][kk], bl[j], c1[i][j]);
                        c1[i][j + 4] = fmaf(a[i][kk], bh[j], c1[i][j + 4]);
                    }
            }
        }
    }

    // prefetch W2 chunk 0 (flies over the transition)
    float4 pw2[4];
    #pragma unroll
    for (int p = 0; p < 4; ++p)
        pw2[p] = *(const float4*)(W2e + p * 1024 + tid * 4);

    __syncthreads();                            // stage-1 LDS reads done
    {   // relu + b1 -> hs row-major (contiguous strips, conflict-free)
        float4 qlo = *(const float4*)(b1 + e * NH + tx1 * 4);
        float4 qhi = *(const float4*)(b1 + e * NH + 64 + tx1 * 4);
        float bb[8] = {qlo.x, qlo.y, qlo.z, qlo.w, qhi.x, qhi.y, qhi.z, qhi.w};
        #pragma unroll
        for (int i = 0; i < 4; ++i) {
            float4 lo, hi;
            lo.x = fmaxf(c1[i][0] + bb[0], 0.f);
            lo.y = fmaxf(c1[i][1] + bb[1], 0.f);
            lo.z = fmaxf(c1[i][2] + bb[2], 0.f);
            lo.w = fmaxf(c1[i][3] + bb[3], 0.f);
            hi.x = fmaxf(c1[i][4] + bb[4], 0.f);
            hi.y = fmaxf(c1[i][5] + bb[5], 0.f);
            hi.z = fmaxf(c1[i][6] + bb[6], 0.f);
            hi.w = fmaxf(c1[i][7] + bb[7], 0.f);
            *(float4*)&sm.s2.hs[ty1 * 4 + i][tx1 * 4]      = lo;
            *(float4*)&sm.s2.hs[ty1 * 4 + i][64 + tx1 * 4] = hi;
        }
    }

    // ---- stage 2: Z[64x256] = H @ W2, 8x8 micro-tile ----
    float z[8][8] = {};
    for (int c = 0; c < NH / KC2; ++c) {
        if (c) __syncthreads();                 // prev chunk consumed
        {
            float* l = &sm.s2.w2s[0][0];
            #pragma unroll
            for (int p = 0; p < 4; ++p)
                *(float4*)(l + p * 1024 + tid * 4) = pw2[p];
        }
        __syncthreads();                        // publish hs (c==0) + w2s
        if (c + 1 < NH / KC2) {
            const float* nw = W2e + (size_t)(c + 1) * KC2 * MO;
            #pragma unroll
            for (int p = 0; p < 4; ++p)
                pw2[p] = *(const float4*)(nw + p * 1024 + tid * 4);
        }
        #pragma unroll 2
        for (int kq = 0; kq < KC2 / 4; ++kq) {
            float a[8][4];
            #pragma unroll
            for (int i = 0; i < 8; ++i) {
                float4 av = *(const float4*)&sm.s2.hs[ty2 * 8 + i][c * KC2 + kq * 4];
                a[i][0] = av.x; a[i][1] = av.y; a[i][2] = av.z; a[i][3] = av.w;
            }
            #pragma unroll
            for (int kk = 0; kk < 4; ++kk) {
                float4 blo = *(const float4*)&sm.s2.w2s[kq * 4 + kk][tx2 * 4];
                float4 bhi = *(const float4*)&sm.s2.w2s[kq * 4 + kk][128 + tx2 * 4];
                float bl[4] = {blo.x, blo.y, blo.z, blo.w};
                float bh[4] = {bhi.x, bhi.y, bhi.z, bhi.w};
                #pragma unroll
                for (int i = 0; i < 8; ++i)
                    #pragma unroll
                    for (int j = 0; j < 4; ++j) {
                        z[i][j]     = fmaf(a[i][kk], bl[j], z[i][j]);
                        z[i][j + 4] = fmaf(a[i][kk], bh[j], z[i][j + 4]);
                    }
            }
        }
    }

    // ---- epilogue: softmax over 256 (32 tx2 lanes x 8 cols), fused @Wout ----
    float4 b2a = *(const float4*)(b2 + e * MO + tx2 * 4);
    float4 b2b = *(const float4*)(b2 + e * MO + 128 + tx2 * 4);
    float bz[8] = {b2a.x, b2a.y, b2a.z, b2a.w, b2b.x, b2b.y, b2b.z, b2b.w};
    float4 q0 = *(const float4*)(Wout + tx2 * 8);
    float4 q1 = *(const float4*)(Wout + tx2 * 8 + 4);
    float4 q2 = *(const float4*)(Wout + 256 + tx2 * 8);
    float4 q3 = *(const float4*)(Wout + 256 + tx2 * 8 + 4);
    float wo0[8] = {q0.x, q0.z, q1.x, q1.z, q2.x, q2.z, q3.x, q3.z};
    float wo1[8] = {q0.y, q0.w, q1.y, q1.w, q2.y, q2.w, q3.y, q3.w};

    #pragma unroll
    for (int i = 0; i < 8; ++i) {
        float m = -1e30f;
        #pragma unroll
        for (int j = 0; j < 8; ++j) { z[i][j] += bz[j]; m = fmaxf(m, z[i][j]); }
        #pragma unroll
        for (int mk = 1; mk < 32; mk <<= 1) m = fmaxf(m, __shfl_xor(m, mk, 64));
        float s = 0.f, w0 = 0.f, w1 = 0.f;
        #pragma unroll
        for (int j = 0; j < 8; ++j) {
            float t = __expf(z[i][j] - m);
            s += t;
            w0 = fmaf(t, wo0[j], w0);
            w1 = fmaf(t, wo1[j], w1);
        }
        #pragma unroll
        for (int mk = 1; mk < 32; mk <<= 1) {
            s  += __shfl_xor(s,  mk, 64);
            w0 += __shfl_xor(w0, mk, 64);
            w1 += __shfl_xor(w1, mk, 64);
        }
        if (tx2 == i) {                  // spread atomics over 8 lanes
            int gi = row0 + ty2 * 8 + i;
            if (gi < cnt) {
                float g = gate_list[e * BN + gi];
                int brow = idx_list[e * BN + gi];
                float inv = 1.f / s;
                atomicAdd(&out[brow * 2 + 0], g * w0 * inv);
                atomicAdd(&out[brow * 2 + 1], g * w1 * inv);
            }
        }
    }
}

extern "C" void kernel_launch(void* const* d_in, const int* in_sizes, int n_in,
                              void* d_out, int out_size, void* d_ws, size_t ws_size,
                              hipStream_t stream) {
    const float* x    = (const float*)d_in[0];
    // d_in[1] = cat_prop, unused by the reference
    const float* wg   = (const float*)d_in[2];
    const float* W1   = (const float*)d_in[3];
    const float* b1   = (const float*)d_in[4];
    const float* W2   = (const float*)d_in[5];
    const float* b2   = (const float*)d_in[6];
    const float* Wout = (const float*)d_in[7];
    const float* bout = (const float*)d_in[8];
    float* out = (float*)d_out;

    char* ws = (char*)d_ws;
    int*   gcount    = (int*)(ws + 0);
    int*   gload     = (int*)(ws + 32);
    float* gimp      = (float*)(ws + 64);
    int*   idx_list  = (int*)(ws + 128);
    float* gate_list = (float*)(ws + 128 + sizeof(int) * NE * BN);

    hipMemsetAsync(ws, 0, 128, stream);
    gate_kernel<<<BN / 128, 256, 0, stream>>>(x, wg, gcount, gload, gimp,
                                              idx_list, gate_list, out, bout);
    loss_kernel<<<1, 64, 0, stream>>>(gimp, gload, out);
    dim3 eg(BN / RT, NE);
    expert_kernel<<<eg, 256, 0, stream>>>(x, W1, b1, W2, b2, Wout,
                                          gcount, idx_list, gate_list, out);
}